// Round 5
// baseline (135.091 us; speedup 1.0000x reference)
//
#include <hip/hip_runtime.h>
#include <math.h>

#define IR_LEN  2000
#define PFRAME  80
#define NFRAMES 300
#define NBATCH  2
#define NROWS   (NBATCH*NFRAMES)     // 600
#define T_TOTAL (NFRAMES*PFRAME)     // 24000
#define NCOEF   25
#define TWO_PI  6.283185307179586f
#define GS2     66                   // G row stride in complexes (even => both d-rows 16B-aligned)

// ---------------------------------------------------------------------------
// Fused min-phase IR kernel: one block per (batch,frame) row.
//   phase E : E[f] = exp(sum_k c[k] e^{-2pi i f k/4096}) for f<=2048 in LDS,
//             mirror-conj for f>2048 (full 4096 spectrum in LDS, no global).
//   stage 1 : G[d][b] = sum_a E[64a+b] w64^{ad}; thread = 4b x 4d where
//             d in {dq,dq+16,dq+32,dq+48} share ONE rotation chain
//             (w64^{16av} = i^{av} = free sign/swap). 2 b128 per a-step.
//   stage 2 : h[64c+d] = (1/4096) Re sum_b G'[d][b] w64^{bc}; thread = 2d x 4c,
//             c in {cg,cg+8,cg+16,cg+24} from one chain via 8th-root constants.
// LDS: one 33.8 KB union buffer (E then G').
// ---------------------------------------------------------------------------
__global__ __launch_bounds__(256) void minphase_fused(
        const float* __restrict__ mc, float* __restrict__ h_out) {
    __shared__ __align__(16) float2 B[64 * GS2];   // 4224 cplx = 33.8 KB
    __shared__ float csh[NCOEF];

    const int row = blockIdx.x;
    const int t   = threadIdx.x;
    if (t < NCOEF) csh[t] = mc[row * NCOEF + t];
    __syncthreads();

    // ---------------- phase E ----------------
    for (int f = t; f <= 2048; f += 256) {
        const float ang = -(TWO_PI / 4096.0f) * (float)f;
        float ws, wc; sincosf(ang, &ws, &wc);          // e^{-2pi i f/4096}
        float cr = 1.0f, ci = 0.0f, Cr = 0.0f, Ci = 0.0f;
        #pragma unroll
        for (int k = 0; k < NCOEF; k++) {
            const float cc = csh[k];
            Cr += cc * cr; Ci += cc * ci;
            const float nr = cr * wc - ci * ws;
            const float ni = cr * ws + ci * wc;
            cr = nr; ci = ni;
        }
        const float m = expf(Cr);
        float si, co; sincosf(Ci, &si, &co);
        B[f] = make_float2(m * co, m * si);
    }
    __syncthreads();
    // mirror: B[2049+i] = conj(B[2047-i])
    for (int i = t; i < 2047; i += 256) {
        const float2 e = B[2047 - i];
        B[2049 + i] = make_float2(e.x, -e.y);
    }
    __syncthreads();

    // ---------------- stage 1 ----------------
    const int bq = t & 15, dq = t >> 4;
    const int b0 = bq * 4;
    float accr[4][4], acci[4][4];                      // [d-variant][b]
    #pragma unroll
    for (int v = 0; v < 4; v++)
        #pragma unroll
        for (int i = 0; i < 4; i++) { accr[v][i] = 0.0f; acci[v][i] = 0.0f; }
    float sw, cw; sincosf((TWO_PI / 64.0f) * (float)dq, &sw, &cw);
    float rr = 1.0f, ri = 0.0f;                        // chain w64^{a*dq}
    for (int a4 = 0; a4 < 64; a4 += 4) {
        #pragma unroll
        for (int u = 0; u < 4; u++) {
            const int a = a4 + u;
            const float4 p0 = *(const float4*)&B[a * 64 + b0];
            const float4 p1 = *(const float4*)&B[a * 64 + b0 + 2];
            const float er[4] = {p0.x, p0.z, p1.x, p1.z};
            const float ei[4] = {p0.y, p0.w, p1.y, p1.w};
            #pragma unroll
            for (int v = 0; v < 4; v++) {
                float fr, fi;                          // chain * i^{a v}
                const int e4 = (u * v) & 3;
                if      (e4 == 0) { fr = rr;  fi = ri;  }
                else if (e4 == 1) { fr = -ri; fi = rr;  }
                else if (e4 == 2) { fr = -rr; fi = -ri; }
                else              { fr = ri;  fi = -rr; }
                #pragma unroll
                for (int i = 0; i < 4; i++) {
                    accr[v][i] += er[i] * fr - ei[i] * fi;
                    acci[v][i] += er[i] * fi + ei[i] * fr;
                }
            }
            const float nr = rr * cw - ri * sw;
            const float ni = rr * sw + ri * cw;
            rr = nr; ri = ni;
        }
    }
    __syncthreads();   // all E reads complete before G overwrites B

    // twiddle-correct G' = G * e^{2pi i b d/4096} and store (stride GS2)
    #pragma unroll
    for (int v = 0; v < 4; v++) {
        const int d = dq + 16 * v;
        float ps, pc; sincosf((TWO_PI / 4096.0f) * (float)d, &ps, &pc);
        float cs, cc; sincosf((TWO_PI / 4096.0f) * (float)(b0 * d), &cs, &cc);
        float xr = cc, xi = cs;
        #pragma unroll
        for (int i = 0; i < 4; i++) {
            const float gr = accr[v][i] * xr - acci[v][i] * xi;
            const float gi = accr[v][i] * xi + acci[v][i] * xr;
            B[d * GS2 + b0 + i] = make_float2(gr, gi);
            const float nr = xr * pc - xi * ps;
            const float ni = xr * ps + xi * pc;
            xr = nr; xi = ni;
        }
    }
    __syncthreads();

    // ---------------- stage 2 ----------------
    {
        const int dh = t & 31;                 // d in {dh, dh+32}
        const int cg = t >> 5;                 // c in {cg, cg+8, cg+16, cg+24}
        float sw2, cw2; sincosf((TWO_PI / 64.0f) * (float)cg, &sw2, &cw2);
        float cr_ = 1.0f, ci_ = 0.0f;          // chain w64^{b*cg}
        float acc[4][2] = {{0,0},{0,0},{0,0},{0,0}};   // [c-variant][d-variant]
        const float S2 = 0.70710678118654752f;

        for (int bb = 0; bb < 64; bb += 8) {
            #pragma unroll
            for (int up = 0; up < 4; up++) {
                const int b = bb + 2 * up;
                const float4 q0 = *(const float4*)&B[dh * GS2 + b];
                const float4 q1 = *(const float4*)&B[(dh + 32) * GS2 + b];
                #pragma unroll
                for (int e = 0; e < 2; e++) {
                    const int u = 2 * up + e;          // b mod 8
                    const float gxr = e ? q0.z : q0.x, gxi = e ? q0.w : q0.y;
                    const float gyr = e ? q1.z : q1.x, gyi = e ? q1.w : q1.y;
                    // F1 = chain * e^{2pi i u/8}
                    float f1r, f1i;
                    if      (u == 0) { f1r = cr_;              f1i = ci_;              }
                    else if (u == 1) { f1r = (cr_ - ci_) * S2; f1i = (cr_ + ci_) * S2; }
                    else if (u == 2) { f1r = -ci_;             f1i = cr_;              }
                    else if (u == 3) { f1r = -(cr_ + ci_) * S2; f1i = (cr_ - ci_) * S2; }
                    else if (u == 4) { f1r = -cr_;             f1i = -ci_;             }
                    else if (u == 5) { f1r = (ci_ - cr_) * S2; f1i = -(cr_ + ci_) * S2; }
                    else if (u == 6) { f1r = ci_;              f1i = -cr_;             }
                    else             { f1r = (cr_ + ci_) * S2; f1i = (ci_ - cr_) * S2; }
                    // F2 = chain * i^b ; F3 = F1 * i^b   (b mod 4 == u mod 4)
                    float f2r, f2i, f3r, f3i;
                    const int b4 = u & 3;
                    if      (b4 == 0) { f2r = cr_;  f2i = ci_;  f3r = f1r;  f3i = f1i;  }
                    else if (b4 == 1) { f2r = -ci_; f2i = cr_;  f3r = -f1i; f3i = f1r;  }
                    else if (b4 == 2) { f2r = -cr_; f2i = -ci_; f3r = -f1r; f3i = -f1i; }
                    else              { f2r = ci_;  f2i = -cr_; f3r = f1i;  f3i = -f1r; }
                    acc[0][0] += gxr * cr_ - gxi * ci_;
                    acc[0][1] += gyr * cr_ - gyi * ci_;
                    acc[1][0] += gxr * f1r - gxi * f1i;
                    acc[1][1] += gyr * f1r - gyi * f1i;
                    acc[2][0] += gxr * f2r - gxi * f2i;
                    acc[2][1] += gyr * f2r - gyi * f2i;
                    acc[3][0] += gxr * f3r - gxi * f3i;
                    acc[3][1] += gyr * f3r - gyi * f3i;
                    const float nr = cr_ * cw2 - ci_ * sw2;
                    const float ni = cr_ * sw2 + ci_ * cw2;
                    cr_ = nr; ci_ = ni;
                }
            }
        }
        const float sc = 1.0f / 4096.0f;
        float* ho = h_out + row * IR_LEN;
        #pragma unroll
        for (int v = 0; v < 4; v++) {
            const int c  = cg + 8 * v;
            const int n0 = 64 * c + dh;
            if (n0 < IR_LEN)      ho[n0]      = acc[v][0] * sc;
            if (n0 + 32 < IR_LEN) ho[n0 + 32] = acc[v][1] * sc;
        }
    }
}

// ---------------------------------------------------------------------------
// B: time-varying FIR (unchanged structure from R4, proven correct).
// ---------------------------------------------------------------------------
__global__ __launch_bounds__(256) void fir_kernel(
        const float* __restrict__ x, const float* __restrict__ h,
        float* __restrict__ y) {
    __shared__ __align__(16) float h0[IR_LEN], h1[IR_LEN];   // 16 KB
    __shared__ __align__(16) float xw[2080];                 // 8.3 KB
    __shared__ __align__(16) float red0[2000], red1[2000];   // 16 KB (25 x 80)

    const int row   = blockIdx.x;              // 0..599
    const int batch = row / NFRAMES;
    const int frame = row - batch * NFRAMES;
    const int t0    = frame * PFRAME;
    const int t     = threadIdx.x;
    const int row1  = (frame + 1 < NFRAMES) ? row + 1 : row;

    const float4* hp0 = (const float4*)(h + (size_t)row  * IR_LEN);
    const float4* hp1 = (const float4*)(h + (size_t)row1 * IR_LEN);
    for (int i = t; i < IR_LEN / 4; i += 256) {
        ((float4*)h0)[i] = hp0[i];
        ((float4*)h1)[i] = hp1[i];
    }
    const float* xb = x + batch * T_TOTAL;
    for (int j = t; j < 2080; j += 256) {
        const int xi = t0 - 1999 + j;
        xw[j] = (xi >= 0 && xi < T_TOTAL) ? xb[xi] : 0.0f;
    }
    __syncthreads();

    if (t < 250) {
        const int o0 = (t % 10) * 8;           // outputs o0..o0+7
        const int kb = (t / 10) * 80;          // taps kb..kb+79
        float s0[8] = {0,0,0,0,0,0,0,0}, s1[8] = {0,0,0,0,0,0,0,0};
        int B = 1996 + o0 - kb;                // mult of 4
        float4 w1 = ((const float4*)xw)[B / 4 + 1];
        float4 w2 = ((const float4*)xw)[B / 4 + 2];
        #pragma unroll 4
        for (int s = 0; s < 20; s++) {
            const float4 w0 = ((const float4*)xw)[B / 4];
            const float4 ha = ((const float4*)h0)[kb / 4 + s];
            const float4 hb = ((const float4*)h1)[kb / 4 + s];
            const float wv[12] = {w0.x, w0.y, w0.z, w0.w,
                                  w1.x, w1.y, w1.z, w1.w,
                                  w2.x, w2.y, w2.z, w2.w};
            const float hav[4] = {ha.x, ha.y, ha.z, ha.w};
            const float hbv[4] = {hb.x, hb.y, hb.z, hb.w};
            #pragma unroll
            for (int jo = 0; jo < 8; jo++) {
                #pragma unroll
                for (int jk = 0; jk < 4; jk++) {
                    const float xv = wv[3 + jo - jk];
                    s0[jo] += hav[jk] * xv;
                    s1[jo] += hbv[jk] * xv;
                }
            }
            w2 = w1; w1 = w0; B -= 4;
        }
        const int rb = (t / 10) * 80 + o0;     // mult of 4
        *(float4*)&red0[rb]     = make_float4(s0[0], s0[1], s0[2], s0[3]);
        *(float4*)&red0[rb + 4] = make_float4(s0[4], s0[5], s0[6], s0[7]);
        *(float4*)&red1[rb]     = make_float4(s1[0], s1[1], s1[2], s1[3]);
        *(float4*)&red1[rb + 4] = make_float4(s1[4], s1[5], s1[6], s1[7]);
    }
    __syncthreads();

    if (t < PFRAME) {
        float S0 = 0.0f, S1 = 0.0f;
        #pragma unroll
        for (int kc = 0; kc < 25; kc++) {
            S0 += red0[kc * 80 + t];
            S1 += red1[kc * 80 + t];
        }
        const float w = (float)t * (1.0f / (float)PFRAME);
        y[batch * T_TOTAL + t0 + t] = (1.0f - w) * S0 + w * S1;
    }
}

extern "C" void kernel_launch(void* const* d_in, const int* in_sizes, int n_in,
                              void* d_out, int out_size, void* d_ws, size_t ws_size,
                              hipStream_t stream) {
    const float* x  = (const float*)d_in[0];   // (2, 24000)
    const float* mc = (const float*)d_in[1];   // (2, 300, 25)
    float* y    = (float*)d_out;               // (2, 24000)
    float* h_ws = (float*)d_ws;                // 600 * 2000 floats = 4.8 MB

    minphase_fused<<<NROWS, 256, 0, stream>>>(mc, h_ws);
    fir_kernel<<<NROWS, 256, 0, stream>>>(x, h_ws, y);
}